// Round 8
// baseline (517.493 us; speedup 1.0000x reference)
//
#include <hip/hip_runtime.h>

#define NCOLS 16
#define NPAIR 120                      // C(16,2)
#define NTRIP 560                      // C(16,3)
#define OUTC  696                      // 16 + 120 + 560 = 174 float4
#define PQ0   4                        // first pair quad   (col 16 / 4)
#define TQ0   34                       // first triple quad (col 136 / 4)

typedef float v4f __attribute__((ext_vector_type(4)));

__device__ __forceinline__ float tnorm(float a, float b, float lam) {
    float m = fmaxf(fmaxf(a, b), lam);          // -> v_max3_f32
    return a * b * __builtin_amdgcn_rcpf(m);
}

// Row-per-lane: each thread computes one full output row in registers.
// No LDS, no shuffles, no index tables. Pair value T(xi,xj) computed once
// per (i,j) and reused by its triples. Two rolling float4 staging quads
// (pair stream -> quads 4..33, triple stream -> quads 34..173), both
// column-linear and 16B-aligned -> 174 global_store_dwordx4 per row with
// compile-time offsets. All loops fully unrolled; every array index is
// compile-time (registers, no scratch).
__global__ __launch_bounds__(256) void dubois_kernel(
    const float* __restrict__ x, const float* __restrict__ lam_p,
    float* __restrict__ out, int B)
{
    const int row = blockIdx.x * 256 + threadIdx.x;
    if (row >= B) return;
    const float lam = lam_p[0];

    const v4f* __restrict__ xr = reinterpret_cast<const v4f*>(x + (size_t)row * NCOLS);
    v4f xq0 = xr[0], xq1 = xr[1], xq2 = xr[2], xq3 = xr[3];

    float xv[NCOLS];
    #pragma unroll
    for (int c = 0; c < 4; ++c) {
        xv[c]      = xq0[c];
        xv[4 + c]  = xq1[c];
        xv[8 + c]  = xq2[c];
        xv[12 + c] = xq3[c];
    }

    v4f* __restrict__ o4 = reinterpret_cast<v4f*>(out + (size_t)row * OUTC);

    // identity columns 0..15
    o4[0] = xq0; o4[1] = xq1; o4[2] = xq2; o4[3] = xq3;

    float sp[4];   // pair-stream staging quad
    float st[4];   // triple-stream staging quad
    int cp = 0;    // pair column counter   (compile-time under unroll)
    int ct = 0;    // triple column counter (compile-time under unroll)

    #pragma unroll
    for (int i = 0; i < NCOLS; ++i) {
        #pragma unroll
        for (int j = i + 1; j < NCOLS; ++j) {
            const float pv = tnorm(xv[i], xv[j], lam);   // computed once

            sp[cp & 3] = pv;
            if ((cp & 3) == 3) {
                v4f t; t[0] = sp[0]; t[1] = sp[1]; t[2] = sp[2]; t[3] = sp[3];
                o4[PQ0 + (cp >> 2)] = t;
            }
            ++cp;

            #pragma unroll
            for (int k = j + 1; k < NCOLS; ++k) {
                st[ct & 3] = tnorm(pv, xv[k], lam);
                if ((ct & 3) == 3) {
                    v4f t; t[0] = st[0]; t[1] = st[1]; t[2] = st[2]; t[3] = st[3];
                    o4[TQ0 + (ct >> 2)] = t;
                }
                ++ct;
            }
        }
    }
    // NPAIR%4==0 and NTRIP%4==0 -> no tail flush needed
}

extern "C" void kernel_launch(void* const* d_in, const int* in_sizes, int n_in,
                              void* d_out, int out_size, void* d_ws, size_t ws_size,
                              hipStream_t stream) {
    const float* x   = (const float*)d_in[0];
    const float* lam = (const float*)d_in[1];
    float* out = (float*)d_out;

    const int B = in_sizes[0] / NCOLS;          // 131072 rows
    const int threads = 256;
    const int blocks  = (B + threads - 1) / threads;   // 512
    dubois_kernel<<<blocks, threads, 0, stream>>>(x, lam, out, B);
}

// Round 10
// 460.024 us; speedup vs baseline: 1.1249x; 1.1249x over previous
//
#include <hip/hip_runtime.h>

#define NCOLS 16
#define OUTC  696        // 16 + 120 + 560
#define TROWS 64         // rows per wave tile
#define NCHUNK 11        // ceil(696/64); last chunk 56 cols (14 quads)

typedef float v4f __attribute__((ext_vector_type(4)));

__device__ __forceinline__ float tnorm(float a, float b, float lam) {
    float m = fmaxf(fmaxf(a, b), lam);          // -> v_max3_f32
    return a * b * __builtin_amdgcn_rcpf(m);
}

// Compile-time column table (indices fold under full unroll -> xv[CONST],
// pair tnorms CSE across the triples that share them).
struct CT { unsigned char i[704], j[704], k[704], op[704]; };
constexpr CT make_ct() {
    CT t{};
    int q = 0;
    for (int i = 0; i < NCOLS; ++i) { t.i[q]=i; t.j[q]=i; t.k[q]=i; t.op[q]=0; ++q; }
    for (int i = 0; i < NCOLS; ++i)
        for (int j = i+1; j < NCOLS; ++j) { t.i[q]=i; t.j[q]=j; t.k[q]=j; t.op[q]=1; ++q; }
    for (int i = 0; i < NCOLS; ++i)
        for (int j = i+1; j < NCOLS; ++j)
            for (int k = j+1; k < NCOLS; ++k) { t.i[q]=i; t.j[q]=j; t.k[q]=k; t.op[q]=2; ++q; }
    for (; q < 704; ++q) { t.i[q]=0; t.j[q]=0; t.k[q]=0; t.op[q]=0; }
    return t;
}
static constexpr CT CTab = make_ct();

// Per-wave 64-row tile: thread = row (cheap per-lane compute, pair reuse),
// LDS [64][64] chunk transpose (quad-XOR swizzle, bank-BW-floor), then
// ds_read_b128 + coalesced global_store_dwordx4 (4 rows x 256B per instr).
// No __syncthreads: tile is wave-private, same-wave DS ops are in-order.
__global__ __launch_bounds__(256) void dubois_kernel(
    const float* __restrict__ x, const float* __restrict__ lam_p,
    float* __restrict__ out, int ntiles)
{
    __shared__ float lds[4][TROWS][64];   // 64 KB/block -> 2 blocks/CU

    const int lane = threadIdx.x & 63;
    const int w    = threadIdx.x >> 6;
    const int tile = blockIdx.x * 4 + w;
    if (tile >= ntiles) return;
    const float lam = lam_p[0];
    const int row0 = tile * TROWS;

    // my row -> registers (4x dwordx4)
    const v4f* __restrict__ xr = reinterpret_cast<const v4f*>(x + (size_t)(row0 + lane) * NCOLS);
    v4f a0 = xr[0], a1 = xr[1], a2 = xr[2], a3 = xr[3];
    float xv[NCOLS];
    #pragma unroll
    for (int c = 0; c < 4; ++c) { xv[c]=a0[c]; xv[4+c]=a1[c]; xv[8+c]=a2[c]; xv[12+c]=a3[c]; }

    const int g = lane >> 4, s = lane & 15;

    #pragma unroll
    for (int ch = 0; ch < NCHUNK; ++ch) {
        const int c0 = ch * 64;
        const int NQ = (ch < NCHUNK - 1) ? 16 : 14;

        // compute my row's 64 cols of this chunk, swizzled b128 writes
        #pragma unroll
        for (int q = 0; q < 16; ++q) {
            if (q < NQ) {                         // folds: compile-time
                v4f o;
                #pragma unroll
                for (int e = 0; e < 4; ++e) {
                    const int c  = c0 + q * 4 + e;
                    const int I  = CTab.i[c], J = CTab.j[c], K = CTab.k[c];
                    const int OP = CTab.op[c];
                    const float pv = tnorm(xv[I], xv[J], lam);
                    const float tv = tnorm(pv, xv[K], lam);
                    o[e] = (OP == 0) ? xv[I] : (OP == 1 ? pv : tv);
                }
                const int pq = q ^ (lane & 15);   // bank spread, bijective per row
                *reinterpret_cast<v4f*>(&lds[w][lane][pq * 4]) = o;
            }
        }

        // transposed flush: instr rr covers rows rr*4+g, cols s*4..s*4+3
        #pragma unroll
        for (int rr = 0; rr < 16; ++rr) {
            const int r = rr * 4 + g;
            if (s < NQ) {
                const int ps = s ^ (r & 15);
                v4f val = *reinterpret_cast<const v4f*>(&lds[w][r][ps * 4]);
                *reinterpret_cast<v4f*>(out + (size_t)(row0 + r) * OUTC + c0 + s * 4) = val;
            }
        }
        // all chunk reads returned before next chunk's writes overwrite (WAR)
        asm volatile("s_waitcnt lgkmcnt(0)" ::: "memory");
    }
}

extern "C" void kernel_launch(void* const* d_in, const int* in_sizes, int n_in,
                              void* d_out, int out_size, void* d_ws, size_t ws_size,
                              hipStream_t stream) {
    const float* x   = (const float*)d_in[0];
    const float* lam = (const float*)d_in[1];
    float* out = (float*)d_out;

    const int B = in_sizes[0] / NCOLS;          // 131072 rows
    const int ntiles = B / TROWS;               // 2048 (B % 64 == 0)
    const int blocks = ntiles / 4;              // 512 blocks x 4 waves
    dubois_kernel<<<blocks, 256, 0, stream>>>(x, lam, out, ntiles);
}